// Round 5
// baseline (216.246 us; speedup 1.0000x reference)
//
#include <hip/hip_runtime.h>

// EnhancedMoEModel: B=524288, D=32, H=64, H2=32, E=8, O=1. fp32 in/out.
// out[b] = sum_e sigmoid(relu(relu(x W1e + b1e) W2e + b2e) W3e + b3e) * probs[b,e]
//
// R14: manual 2-expert interleave. R13b (48us, MfmaUtil 31%, VGPR=32)
// showed the compiler unrolled the expert loop WITHOUT interleaving the
// chains (register-minimizing schedule -> one expert's live set = 32 regs,
// 3 serial MFMA stages per expert = latency-bound). This version processes
// experts in pairs with explicitly separate register sets: at every stage
// 4 independent MFMAs (2 experts x 2 row-tiles) issue back-to-back.
// Pair loop fully unrolled (all indices compile-time).
//
// Fragment math (verified R8/R10 end-to-end, dtype-independent C/D layout):
// 16x16x32 MFMA with A[m=lane&15][k=8q+j], B[k=8q+j][n=lane&15],
// D[m=4q+r][n]: per-lane reg r. Hidden-unit column permutation
// hmap(mt,n)=32(mt>>1)+8(n>>2)+4(mt&1)+(n&3) makes layer-N output registers
// exactly the next layer's B-fragment.
//
// LDS/ws image layout (byte offsets):
//   [0,      65536): weight frags, 16B each, F = addr/16:
//       w1: F = e*256 + 64*mt + 16*q + n
//       w2: F = 2048 + e*256 + 128*kb2 + 64*mt2 + 16*q + n
//   [65536, 67584): b1 frags  f32x4, idx = e*16 + mt*4 + q
//   [67584, 68608): b2 frags  f32x4, idx = e*8 + mt2*4 + q
//   [68608, 69120): a3 frags  f16x8, idx = e*4 + q
//   [69120, 69152): b3[0..7] f32

typedef __attribute__((ext_vector_type(8))) _Float16 f16x8;
typedef __attribute__((ext_vector_type(2))) __fp16 h16x2;
typedef __attribute__((ext_vector_type(4))) float f32x4;

__device__ __forceinline__ unsigned pkh(float lo, float hi) {
    union { h16x2 v; unsigned u; } t;
    t.v = __builtin_amdgcn_cvt_pkrtz(lo, hi);
    return t.u;
}

// packed relu on 2 x f16 (relu-after-pack == relu-before-pack for RTZ)
__device__ __forceinline__ unsigned relu2(unsigned a) {
    unsigned r;
    asm("v_pk_max_f16 %0, %1, 0" : "=v"(r) : "v"(a));
    return r;
}

__device__ __forceinline__ float sigf(float s) {
    return 1.f / (1.f + __expf(-s));
}

#define MFMA32(a, b, c) __builtin_amdgcn_mfma_f32_16x16x32_f16((a), (b), (c), 0, 0, 0)

__global__ __launch_bounds__(1024)
void build_image(const float* __restrict__ W1, const float* __restrict__ b1,
                 const float* __restrict__ W2, const float* __restrict__ b2,
                 const float* __restrict__ W3, const float* __restrict__ b3,
                 char* __restrict__ ws) {
    const int tid = threadIdx.x;
    #pragma unroll
    for (int k = 0; k < 4; ++k) {
        const int F = tid + k * 1024;
        const int e = (F >> 8) & 7, s = F & 255;
        const int qq = (s >> 4) & 3, nn = s & 15;
        const float* src;
        int stride;
        if (F < 2048) {          // W1[e][d=8qq+j][hmap(mt,nn)], j strides d
            const int mt = s >> 6;
            const int h = 32 * (mt >> 1) + 8 * (nn >> 2) + 4 * (mt & 1) + (nn & 3);
            src = W1 + (e * 32 + 8 * qq) * 64 + h;
            stride = 64;
        } else {                 // W2[e][h=32kb2+8qq+j][h2map(mt2,nn)], j strides h
            const int kb2 = (s >> 7) & 1, mt2 = (s >> 6) & 1;
            const int h2 = 8 * (nn >> 2) + 4 * mt2 + (nn & 3);
            src = W2 + (e * 64 + 32 * kb2 + 8 * qq) * 32 + h2;
            stride = 32;
        }
        union { f16x8 v; unsigned u[4]; } t;
        t.u[0] = pkh(src[0 * stride], src[1 * stride]);
        t.u[1] = pkh(src[2 * stride], src[3 * stride]);
        t.u[2] = pkh(src[4 * stride], src[5 * stride]);
        t.u[3] = pkh(src[6 * stride], src[7 * stride]);
        *(f16x8*)(ws + F * 16) = t.v;
    }
    if (tid < 128) {                       // b1 frags
        const int e = tid >> 4, mt = (tid >> 2) & 3, q = tid & 3;
        *(f32x4*)(ws + 65536 + tid * 16) =
            *(const f32x4*)(b1 + e * 64 + 32 * (mt >> 1) + 4 * (mt & 1) + 8 * q);
    } else if (tid < 192) {                // b2 frags
        const int i = tid - 128, e = i >> 3, mt2 = (i >> 2) & 1, q = i & 3;
        *(f32x4*)(ws + 67584 + i * 16) =
            *(const f32x4*)(b2 + e * 32 + 4 * mt2 + 8 * q);
    } else if (tid < 224) {                // a3 frags (pre-packed f16)
        const int i = tid - 192, e = i >> 2, q = i & 3;
        const f32x4 lo = *(const f32x4*)(W3 + e * 32 + 8 * q);
        const f32x4 hi = *(const f32x4*)(W3 + e * 32 + 8 * q + 4);
        union { f16x8 v; unsigned u[4]; } a;
        a.u[0] = pkh(lo.x, lo.y); a.u[1] = pkh(lo.z, lo.w);
        a.u[2] = pkh(hi.x, hi.y); a.u[3] = pkh(hi.z, hi.w);
        *(f16x8*)(ws + 68608 + i * 16) = a.v;
    } else if (tid < 232) {                // b3
        const int i = tid - 224;
        *(float*)(ws + 69120 + i * 4) = b3[i];
    }
}

__global__ __launch_bounds__(1024, 8)
void moe_fused(const float* __restrict__ x, const float* __restrict__ probs,
               const char* __restrict__ img, float* __restrict__ out) {
    __shared__ __attribute__((aligned(16))) char ldsraw[69632];
    const int tid = threadIdx.x;
    const int w = tid >> 6, lane = tid & 63, n = lane & 15, q = lane >> 4;

    // ---- prologue: linear coalesced copy of the prebuilt image.
    #pragma unroll
    for (int k = 0; k < 4; ++k) {
        const int off = tid * 16 + k * 16384;
        *(f32x4*)(ldsraw + off) = *(const f32x4*)(img + off);
    }
    if (tid < 226) {                        // tail 3616 B incl. b3
        const int off = 65536 + tid * 16;
        *(f32x4*)(ldsraw + off) = *(const f32x4*)(img + off);
    }

    // ---- per-wave x tiles: wave owns rows rb..rb+31 (two 16-row tiles).
    const int rb = blockIdx.x * 512 + w * 32;
    const float* xp0 = x + (size_t)(rb + n) * 32 + q * 8;
    const float* xp1 = xp0 + 16 * 32;
    const f32x4 xa0 = *(const f32x4*)xp0, xb0 = *(const f32x4*)(xp0 + 4);
    const f32x4 xa1 = *(const f32x4*)xp1, xb1 = *(const f32x4*)(xp1 + 4);
    union { f16x8 v; unsigned u[4]; } xf0, xf1;
    xf0.u[0] = pkh(xa0.x, xa0.y); xf0.u[1] = pkh(xa0.z, xa0.w);
    xf0.u[2] = pkh(xb0.x, xb0.y); xf0.u[3] = pkh(xb0.z, xb0.w);
    xf1.u[0] = pkh(xa1.x, xa1.y); xf1.u[1] = pkh(xa1.z, xa1.w);
    xf1.u[2] = pkh(xb1.x, xb1.y); xf1.u[3] = pkh(xb1.z, xb1.w);

    __syncthreads();

    const short* wl = (const short*)ldsraw + (n * 8 + q * 128);
    const char* bb1 = ldsraw + 65536 + q * 16;   // + e*256 + mt*64
    const char* bb2 = ldsraw + 67584 + q * 16;   // + e*128 + mt2*64
    const char* ba3 = ldsraw + 68608 + q * 16;   // + e*64
    const float* b3l = (const float*)(ldsraw + 69120);
    const float* pba = probs + (size_t)(rb + n) * 8;
    float r0 = 0.f, r1 = 0.f;

    // ---- expert pairs, fully unrolled: 4 independent MFMAs per stage.
    #pragma unroll
    for (int ep = 0; ep < 4; ++ep) {
        const int e0 = 2 * ep;
        const short* wea = wl + e0 * 2048;
        const short* web = wea + 2048;
        const float pa0 = pba[e0],     pa1 = pba[e0 + 128];
        const float pc0 = pba[e0 + 1], pc1 = pba[e0 + 129];

        // Layer 1: 4 mt-tiles x {expert a, expert b} x {row-tile 0,1}.
        union { f16x8 v; unsigned u[4]; } P0a[2], P1a[2], P0b[2], P1b[2];
        #pragma unroll
        for (int mt = 0; mt < 4; ++mt) {
            const f16x8 w1a = *(const f16x8*)(wea + mt * 512);
            const f16x8 w1b = *(const f16x8*)(web + mt * 512);
            const f32x4 bfa = *(const f32x4*)(bb1 + e0 * 256 + mt * 64);
            const f32x4 bfb = *(const f32x4*)(bb1 + e0 * 256 + 256 + mt * 64);
            const f32x4 c0a = MFMA32(w1a, xf0.v, bfa);
            const f32x4 c1a = MFMA32(w1a, xf1.v, bfa);
            const f32x4 c0b = MFMA32(w1b, xf0.v, bfb);
            const f32x4 c1b = MFMA32(w1b, xf1.v, bfb);
            P0a[mt >> 1].u[(mt & 1) * 2 + 0] = relu2(pkh(c0a.x, c0a.y));
            P0a[mt >> 1].u[(mt & 1) * 2 + 1] = relu2(pkh(c0a.z, c0a.w));
            P1a[mt >> 1].u[(mt & 1) * 2 + 0] = relu2(pkh(c1a.x, c1a.y));
            P1a[mt >> 1].u[(mt & 1) * 2 + 1] = relu2(pkh(c1a.z, c1a.w));
            P0b[mt >> 1].u[(mt & 1) * 2 + 0] = relu2(pkh(c0b.x, c0b.y));
            P0b[mt >> 1].u[(mt & 1) * 2 + 1] = relu2(pkh(c0b.z, c0b.w));
            P1b[mt >> 1].u[(mt & 1) * 2 + 0] = relu2(pkh(c1b.x, c1b.y));
            P1b[mt >> 1].u[(mt & 1) * 2 + 1] = relu2(pkh(c1b.z, c1b.w));
        }

        // Layer 2: 2 mt2 x 2 kb2, both experts, both row-tiles.
        union { f16x8 v; unsigned u[4]; } PC0a, PC1a, PC0b, PC1b;
        #pragma unroll
        for (int mt2 = 0; mt2 < 2; ++mt2) {
            const f32x4 bfa = *(const f32x4*)(bb2 + e0 * 128 + mt2 * 64);
            const f32x4 bfb = *(const f32x4*)(bb2 + e0 * 128 + 128 + mt2 * 64);
            f32x4 c0a = bfa, c1a = bfa, c0b = bfb, c1b = bfb;
            #pragma unroll
            for (int kb2 = 0; kb2 < 2; ++kb2) {
                const f16x8 w2a =
                    *(const f16x8*)(wea + 16384 + mt2 * 512 + kb2 * 1024);
                const f16x8 w2b =
                    *(const f16x8*)(web + 16384 + mt2 * 512 + kb2 * 1024);
                c0a = MFMA32(w2a, P0a[kb2].v, c0a);
                c1a = MFMA32(w2a, P1a[kb2].v, c1a);
                c0b = MFMA32(w2b, P0b[kb2].v, c0b);
                c1b = MFMA32(w2b, P1b[kb2].v, c1b);
            }
            PC0a.u[mt2 * 2 + 0] = relu2(pkh(c0a.x, c0a.y));
            PC0a.u[mt2 * 2 + 1] = relu2(pkh(c0a.z, c0a.w));
            PC1a.u[mt2 * 2 + 0] = relu2(pkh(c1a.x, c1a.y));
            PC1a.u[mt2 * 2 + 1] = relu2(pkh(c1a.z, c1a.w));
            PC0b.u[mt2 * 2 + 0] = relu2(pkh(c0b.x, c0b.y));
            PC0b.u[mt2 * 2 + 1] = relu2(pkh(c0b.z, c0b.w));
            PC1b.u[mt2 * 2 + 0] = relu2(pkh(c1b.x, c1b.y));
            PC1b.u[mt2 * 2 + 1] = relu2(pkh(c1b.z, c1b.w));
        }

        // Layer 3: pre-packed w3 frags; b3 seeded into C operand.
        const f16x8 a3a = *(const f16x8*)(ba3 + e0 * 64);
        const f16x8 a3b = *(const f16x8*)(ba3 + e0 * 64 + 64);
        const float bba = b3l[e0], bbb = b3l[e0 + 1];
        const f32x4 cba = {bba, bba, bba, bba};
        const f32x4 cbb = {bbb, bbb, bbb, bbb};
        const f32x4 s0a = MFMA32(a3a, PC0a.v, cba);
        const f32x4 s1a = MFMA32(a3a, PC1a.v, cba);
        const f32x4 s0b = MFMA32(a3b, PC0b.v, cbb);
        const f32x4 s1b = MFMA32(a3b, PC1b.v, cbb);

        r0 = fmaf(sigf(s0a.x), pa0, r0);
        r1 = fmaf(sigf(s1a.x), pa1, r1);
        r0 = fmaf(sigf(s0b.x), pc0, r0);
        r1 = fmaf(sigf(s1b.x), pc1, r1);
    }

    if (q == 0) {
        out[rb + n] = r0;
        out[rb + 16 + n] = r1;
    }
}

extern "C" void kernel_launch(void* const* d_in, const int* in_sizes, int n_in,
                              void* d_out, int out_size, void* d_ws, size_t ws_size,
                              hipStream_t stream) {
    const float* x     = (const float*)d_in[0];
    const float* probs = (const float*)d_in[1];
    const float* W1    = (const float*)d_in[2];
    const float* b1    = (const float*)d_in[3];
    const float* W2    = (const float*)d_in[4];
    const float* b2    = (const float*)d_in[5];
    const float* W3    = (const float*)d_in[6];
    const float* b3    = (const float*)d_in[7];

    hipLaunchKernelGGL(build_image, dim3(1), dim3(1024), 0, stream,
                       W1, b1, W2, b2, W3, b3, (char*)d_ws);
    const int nrows = in_sizes[0] / 32;          // 524288
    hipLaunchKernelGGL(moe_fused, dim3(nrows / 512), dim3(1024), 0, stream,
                       x, probs, (const char*)d_ws, (float*)d_out);
}

// Round 7
// 140.084 us; speedup vs baseline: 1.5437x; 1.5437x over previous
//
#include <hip/hip_runtime.h>

// EnhancedMoEModel: B=524288, D=32, H=64, H2=32, E=8, O=1. fp32 in/out.
// out[b] = sum_e sigmoid(relu(relu(x W1e + b1e) W2e + b2e) W3e + b3e) * probs[b,e]
//
// R16: R15's 4-chain interleave (2 experts x 2 row-tiles, fully unrolled)
// at 512-thread blocks with launch_bounds(512,4): VGPR cap 128 (no spill,
// unlike R14's 64-cap scratch blowup), 2 blocks/CU (LDS 2x69.6KB=139KB),
// 16 waves/CU. R15's (1024,4) config produced NaN despite byte-identical
// source passing at (1024,8) -> codegen-path issue at forced waves-per-eu
// on 1024-thread blocks; this reaches the same occupancy/register state
// via the standard small-block path. Kernel body unchanged from R14/R15.
//
// Fragment math (verified R8/R10 end-to-end, dtype-independent C/D layout):
// 16x16x32 MFMA with A[m=lane&15][k=8q+j], B[k=8q+j][n=lane&15],
// D[m=4q+r][n]: per-lane reg r. Hidden-unit column permutation
// hmap(mt,n)=32(mt>>1)+8(n>>2)+4(mt&1)+(n&3) makes layer-N output registers
// exactly the next layer's B-fragment.
//
// LDS/ws image layout (byte offsets):
//   [0,      65536): weight frags, 16B each, F = addr/16:
//       w1: F = e*256 + 64*mt + 16*q + n
//       w2: F = 2048 + e*256 + 128*kb2 + 64*mt2 + 16*q + n
//   [65536, 67584): b1 frags  f32x4, idx = e*16 + mt*4 + q
//   [67584, 68608): b2 frags  f32x4, idx = e*8 + mt2*4 + q
//   [68608, 69120): a3 frags  f16x8, idx = e*4 + q
//   [69120, 69152): b3[0..7] f32

typedef __attribute__((ext_vector_type(8))) _Float16 f16x8;
typedef __attribute__((ext_vector_type(2))) __fp16 h16x2;
typedef __attribute__((ext_vector_type(4))) float f32x4;

__device__ __forceinline__ unsigned pkh(float lo, float hi) {
    union { h16x2 v; unsigned u; } t;
    t.v = __builtin_amdgcn_cvt_pkrtz(lo, hi);
    return t.u;
}

// packed relu on 2 x f16 (relu-after-pack == relu-before-pack for RTZ)
__device__ __forceinline__ unsigned relu2(unsigned a) {
    unsigned r;
    asm("v_pk_max_f16 %0, %1, 0" : "=v"(r) : "v"(a));
    return r;
}

__device__ __forceinline__ float sigf(float s) {
    return 1.f / (1.f + __expf(-s));
}

#define MFMA32(a, b, c) __builtin_amdgcn_mfma_f32_16x16x32_f16((a), (b), (c), 0, 0, 0)

__global__ __launch_bounds__(1024)
void build_image(const float* __restrict__ W1, const float* __restrict__ b1,
                 const float* __restrict__ W2, const float* __restrict__ b2,
                 const float* __restrict__ W3, const float* __restrict__ b3,
                 char* __restrict__ ws) {
    const int tid = threadIdx.x;
    #pragma unroll
    for (int k = 0; k < 4; ++k) {
        const int F = tid + k * 1024;
        const int e = (F >> 8) & 7, s = F & 255;
        const int qq = (s >> 4) & 3, nn = s & 15;
        const float* src;
        int stride;
        if (F < 2048) {          // W1[e][d=8qq+j][hmap(mt,nn)], j strides d
            const int mt = s >> 6;
            const int h = 32 * (mt >> 1) + 8 * (nn >> 2) + 4 * (mt & 1) + (nn & 3);
            src = W1 + (e * 32 + 8 * qq) * 64 + h;
            stride = 64;
        } else {                 // W2[e][h=32kb2+8qq+j][h2map(mt2,nn)], j strides h
            const int kb2 = (s >> 7) & 1, mt2 = (s >> 6) & 1;
            const int h2 = 8 * (nn >> 2) + 4 * mt2 + (nn & 3);
            src = W2 + (e * 64 + 32 * kb2 + 8 * qq) * 32 + h2;
            stride = 32;
        }
        union { f16x8 v; unsigned u[4]; } t;
        t.u[0] = pkh(src[0 * stride], src[1 * stride]);
        t.u[1] = pkh(src[2 * stride], src[3 * stride]);
        t.u[2] = pkh(src[4 * stride], src[5 * stride]);
        t.u[3] = pkh(src[6 * stride], src[7 * stride]);
        *(f16x8*)(ws + F * 16) = t.v;
    }
    if (tid < 128) {                       // b1 frags
        const int e = tid >> 4, mt = (tid >> 2) & 3, q = tid & 3;
        *(f32x4*)(ws + 65536 + tid * 16) =
            *(const f32x4*)(b1 + e * 64 + 32 * (mt >> 1) + 4 * (mt & 1) + 8 * q);
    } else if (tid < 192) {                // b2 frags
        const int i = tid - 128, e = i >> 3, mt2 = (i >> 2) & 1, q = i & 3;
        *(f32x4*)(ws + 67584 + i * 16) =
            *(const f32x4*)(b2 + e * 32 + 4 * mt2 + 8 * q);
    } else if (tid < 224) {                // a3 frags (pre-packed f16)
        const int i = tid - 192, e = i >> 2, q = i & 3;
        const f32x4 lo = *(const f32x4*)(W3 + e * 32 + 8 * q);
        const f32x4 hi = *(const f32x4*)(W3 + e * 32 + 8 * q + 4);
        union { f16x8 v; unsigned u[4]; } a;
        a.u[0] = pkh(lo.x, lo.y); a.u[1] = pkh(lo.z, lo.w);
        a.u[2] = pkh(hi.x, hi.y); a.u[3] = pkh(hi.z, hi.w);
        *(f16x8*)(ws + 68608 + i * 16) = a.v;
    } else if (tid < 232) {                // b3
        const int i = tid - 224;
        *(float*)(ws + 69120 + i * 4) = b3[i];
    }
}

__global__ __launch_bounds__(512, 4)
void moe_fused(const float* __restrict__ x, const float* __restrict__ probs,
               const char* __restrict__ img, float* __restrict__ out) {
    __shared__ __attribute__((aligned(16))) char ldsraw[69632];
    const int tid = threadIdx.x;
    const int w = tid >> 6, lane = tid & 63, n = lane & 15, q = lane >> 4;

    // ---- prologue: linear coalesced copy of the prebuilt image.
    #pragma unroll
    for (int k = 0; k < 8; ++k) {
        const int off = tid * 16 + k * 8192;
        *(f32x4*)(ldsraw + off) = *(const f32x4*)(img + off);
    }
    if (tid < 226) {                        // tail 3616 B incl. b3
        const int off = 65536 + tid * 16;
        *(f32x4*)(ldsraw + off) = *(const f32x4*)(img + off);
    }

    // ---- per-wave x tiles: wave owns rows rb..rb+31 (two 16-row tiles).
    const int rb = blockIdx.x * 256 + w * 32;
    const float* xp0 = x + (size_t)(rb + n) * 32 + q * 8;
    const float* xp1 = xp0 + 16 * 32;
    const f32x4 xa0 = *(const f32x4*)xp0, xb0 = *(const f32x4*)(xp0 + 4);
    const f32x4 xa1 = *(const f32x4*)xp1, xb1 = *(const f32x4*)(xp1 + 4);
    union { f16x8 v; unsigned u[4]; } xf0, xf1;
    xf0.u[0] = pkh(xa0.x, xa0.y); xf0.u[1] = pkh(xa0.z, xa0.w);
    xf0.u[2] = pkh(xb0.x, xb0.y); xf0.u[3] = pkh(xb0.z, xb0.w);
    xf1.u[0] = pkh(xa1.x, xa1.y); xf1.u[1] = pkh(xa1.z, xa1.w);
    xf1.u[2] = pkh(xb1.x, xb1.y); xf1.u[3] = pkh(xb1.z, xb1.w);

    __syncthreads();

    const short* wl = (const short*)ldsraw + (n * 8 + q * 128);
    const char* bb1 = ldsraw + 65536 + q * 16;   // + e*256 + mt*64
    const char* bb2 = ldsraw + 67584 + q * 16;   // + e*128 + mt2*64
    const char* ba3 = ldsraw + 68608 + q * 16;   // + e*64
    const float* b3l = (const float*)(ldsraw + 69120);
    const float* pba = probs + (size_t)(rb + n) * 8;
    float r0 = 0.f, r1 = 0.f;

    // ---- expert pairs, fully unrolled: 4 independent MFMAs per stage.
    #pragma unroll
    for (int ep = 0; ep < 4; ++ep) {
        const int e0 = 2 * ep;
        const short* wea = wl + e0 * 2048;
        const short* web = wea + 2048;
        const float pa0 = pba[e0],     pa1 = pba[e0 + 128];
        const float pc0 = pba[e0 + 1], pc1 = pba[e0 + 129];

        // Layer 1: 4 mt-tiles x {expert a, expert b} x {row-tile 0,1}.
        union { f16x8 v; unsigned u[4]; } P0a[2], P1a[2], P0b[2], P1b[2];
        #pragma unroll
        for (int mt = 0; mt < 4; ++mt) {
            const f16x8 w1a = *(const f16x8*)(wea + mt * 512);
            const f16x8 w1b = *(const f16x8*)(web + mt * 512);
            const f32x4 bfa = *(const f32x4*)(bb1 + e0 * 256 + mt * 64);
            const f32x4 bfb = *(const f32x4*)(bb1 + e0 * 256 + 256 + mt * 64);
            const f32x4 c0a = MFMA32(w1a, xf0.v, bfa);
            const f32x4 c1a = MFMA32(w1a, xf1.v, bfa);
            const f32x4 c0b = MFMA32(w1b, xf0.v, bfb);
            const f32x4 c1b = MFMA32(w1b, xf1.v, bfb);
            P0a[mt >> 1].u[(mt & 1) * 2 + 0] = relu2(pkh(c0a.x, c0a.y));
            P0a[mt >> 1].u[(mt & 1) * 2 + 1] = relu2(pkh(c0a.z, c0a.w));
            P1a[mt >> 1].u[(mt & 1) * 2 + 0] = relu2(pkh(c1a.x, c1a.y));
            P1a[mt >> 1].u[(mt & 1) * 2 + 1] = relu2(pkh(c1a.z, c1a.w));
            P0b[mt >> 1].u[(mt & 1) * 2 + 0] = relu2(pkh(c0b.x, c0b.y));
            P0b[mt >> 1].u[(mt & 1) * 2 + 1] = relu2(pkh(c0b.z, c0b.w));
            P1b[mt >> 1].u[(mt & 1) * 2 + 0] = relu2(pkh(c1b.x, c1b.y));
            P1b[mt >> 1].u[(mt & 1) * 2 + 1] = relu2(pkh(c1b.z, c1b.w));
        }

        // Layer 2: 2 mt2 x 2 kb2, both experts, both row-tiles.
        union { f16x8 v; unsigned u[4]; } PC0a, PC1a, PC0b, PC1b;
        #pragma unroll
        for (int mt2 = 0; mt2 < 2; ++mt2) {
            const f32x4 bfa = *(const f32x4*)(bb2 + e0 * 128 + mt2 * 64);
            const f32x4 bfb = *(const f32x4*)(bb2 + e0 * 128 + 128 + mt2 * 64);
            f32x4 c0a = bfa, c1a = bfa, c0b = bfb, c1b = bfb;
            #pragma unroll
            for (int kb2 = 0; kb2 < 2; ++kb2) {
                const f16x8 w2a =
                    *(const f16x8*)(wea + 16384 + mt2 * 512 + kb2 * 1024);
                const f16x8 w2b =
                    *(const f16x8*)(web + 16384 + mt2 * 512 + kb2 * 1024);
                c0a = MFMA32(w2a, P0a[kb2].v, c0a);
                c1a = MFMA32(w2a, P1a[kb2].v, c1a);
                c0b = MFMA32(w2b, P0b[kb2].v, c0b);
                c1b = MFMA32(w2b, P1b[kb2].v, c1b);
            }
            PC0a.u[mt2 * 2 + 0] = relu2(pkh(c0a.x, c0a.y));
            PC0a.u[mt2 * 2 + 1] = relu2(pkh(c0a.z, c0a.w));
            PC1a.u[mt2 * 2 + 0] = relu2(pkh(c1a.x, c1a.y));
            PC1a.u[mt2 * 2 + 1] = relu2(pkh(c1a.z, c1a.w));
            PC0b.u[mt2 * 2 + 0] = relu2(pkh(c0b.x, c0b.y));
            PC0b.u[mt2 * 2 + 1] = relu2(pkh(c0b.z, c0b.w));
            PC1b.u[mt2 * 2 + 0] = relu2(pkh(c1b.x, c1b.y));
            PC1b.u[mt2 * 2 + 1] = relu2(pkh(c1b.z, c1b.w));
        }

        // Layer 3: pre-packed w3 frags; b3 seeded into C operand.
        const f16x8 a3a = *(const f16x8*)(ba3 + e0 * 64);
        const f16x8 a3b = *(const f16x8*)(ba3 + e0 * 64 + 64);
        const float bba = b3l[e0], bbb = b3l[e0 + 1];
        const f32x4 cba = {bba, bba, bba, bba};
        const f32x4 cbb = {bbb, bbb, bbb, bbb};
        const f32x4 s0a = MFMA32(a3a, PC0a.v, cba);
        const f32x4 s1a = MFMA32(a3a, PC1a.v, cba);
        const f32x4 s0b = MFMA32(a3b, PC0b.v, cbb);
        const f32x4 s1b = MFMA32(a3b, PC1b.v, cbb);

        r0 = fmaf(sigf(s0a.x), pa0, r0);
        r1 = fmaf(sigf(s1a.x), pa1, r1);
        r0 = fmaf(sigf(s0b.x), pc0, r0);
        r1 = fmaf(sigf(s1b.x), pc1, r1);
    }

    if (q == 0) {
        out[rb + n] = r0;
        out[rb + 16 + n] = r1;
    }
}

extern "C" void kernel_launch(void* const* d_in, const int* in_sizes, int n_in,
                              void* d_out, int out_size, void* d_ws, size_t ws_size,
                              hipStream_t stream) {
    const float* x     = (const float*)d_in[0];
    const float* probs = (const float*)d_in[1];
    const float* W1    = (const float*)d_in[2];
    const float* b1    = (const float*)d_in[3];
    const float* W2    = (const float*)d_in[4];
    const float* b2    = (const float*)d_in[5];
    const float* W3    = (const float*)d_in[6];
    const float* b3    = (const float*)d_in[7];

    hipLaunchKernelGGL(build_image, dim3(1), dim3(1024), 0, stream,
                       W1, b1, W2, b2, W3, b3, (char*)d_ws);
    const int nrows = in_sizes[0] / 32;          // 524288
    hipLaunchKernelGGL(moe_fused, dim3(nrows / 256), dim3(512), 0, stream,
                       x, probs, (const char*)d_ws, (float*)d_out);
}